// Round 5
// baseline (374.245 us; speedup 1.0000x reference)
//
#include <hip/hip_runtime.h>
#include <hip/hip_bf16.h>
#include <stdint.h>

typedef __bf16 bf16_t;
typedef __attribute__((ext_vector_type(8))) __bf16 bf16x8;
typedef __attribute__((ext_vector_type(4))) float f32x4;
typedef __attribute__((ext_vector_type(8))) unsigned short u16x8;

#define S_LEN 2048
#define DIM   4096
#define QKVN  6144
#define NHEAD 32
#define HDIM  128

typedef __attribute__((address_space(1))) unsigned int as1_u32;
typedef __attribute__((address_space(3))) unsigned int as3_u32;

__device__ __forceinline__ unsigned short f2bf(float f) {
  unsigned u = __builtin_bit_cast(unsigned, f);
  u += 0x7fffu + ((u >> 16) & 1u);
  return (unsigned short)(u >> 16);
}

__device__ __forceinline__ void gload_lds16(const void* g, void* l) {
  __builtin_amdgcn_global_load_lds(
      (as1_u32*)(unsigned long long)(uintptr_t)g,
      (as3_u32*)(unsigned int)(uintptr_t)l,
      16, 0, 0);
}

__global__ __launch_bounds__(256) void cvt_kernel(const float* __restrict__ in,
                                                  unsigned short* __restrict__ out,
                                                  int n4) {
  int idx = blockIdx.x * 256 + threadIdx.x;
  int stride = gridDim.x * 256;
  for (int i = idx; i < n4; i += stride) {
    float4 v = ((const float4*)in)[i];
    ushort4 o;
    o.x = f2bf(v.x); o.y = f2bf(v.y); o.z = f2bf(v.z); o.w = f2bf(v.w);
    ((ushort4*)out)[i] = o;
  }
}

// ------- 128x128 register-pipelined GEMM, BK=32, 4 waves (2M x 2N) -------
// C(M,N) = A(M,K) * B(N,K)^T. LDS = 3 slots x (A 128x32 + B 128x32) = 48KB.
// body(t): ds_read frags(t+1) | stage(t+3)->slotW | MFMA frags(t) overlaps |
// lgkmcnt(0); vmcnt(4) [stage(t+2) landed, stage(t+3) in flight]; barrier.
// Swizzle key (row>>1)&3 on both stage-source and frag-read (R4: conflicts=0).
__device__ __forceinline__ bf16x8 frag_ld(const char* base, int row, int lg) {
  return *(const bf16x8*)(base + row * 64 + ((lg ^ ((row >> 1) & 3)) << 4));
}

__device__ __forceinline__ void load_frags(const char* slot, int wm, int wn,
                                           int lg, int lr, bf16x8* af, bf16x8* bf) {
#pragma unroll
  for (int i = 0; i < 4; ++i) af[i] = frag_ld(slot, wm * 64 + i * 16 + lr, lg);
#pragma unroll
  for (int i = 0; i < 4; ++i) bf[i] = frag_ld(slot + 8192, wn * 64 + i * 16 + lr, lg);
}

__device__ __forceinline__ void stage_slot(const bf16_t* a0, const bf16_t* b0,
                                           long ldk64, int k0, char* slot, int tid) {
  gload_lds16(a0 + k0,         slot + tid * 16);
  gload_lds16(a0 + ldk64 + k0, slot + 4096 + tid * 16);
  gload_lds16(b0 + k0,         slot + 8192 + tid * 16);
  gload_lds16(b0 + ldk64 + k0, slot + 12288 + tid * 16);
}

__device__ __forceinline__ void mfma16(const bf16x8* af, const bf16x8* bf,
                                       f32x4 (*acc)[4]) {
#pragma unroll
  for (int mf = 0; mf < 4; ++mf)
#pragma unroll
    for (int nf = 0; nf < 4; ++nf)
      acc[mf][nf] = __builtin_amdgcn_mfma_f32_16x16x32_bf16(af[mf], bf[nf],
                                                            acc[mf][nf], 0, 0, 0);
}

template <int OUTF32>
__global__ __launch_bounds__(256, 2) void gemm_pipe(const bf16_t* __restrict__ A,
                                                    const bf16_t* __restrict__ B,
                                                    void* __restrict__ Cout,
                                                    int M, int N, int K, int nxt) {
  __shared__ char lds[49152];
  const int tid = threadIdx.x;
  const int lane = tid & 63, w = tid >> 6;
  const int wm = w >> 1, wn = w & 1;
  const int lg = lane >> 4, lr = lane & 15;
  const int nwg = gridDim.x;
  const int orig = blockIdx.x;
  const int wgid = (orig & 7) * (nwg >> 3) + (orig >> 3);  // nwg % 8 == 0
  const int bx = wgid % nxt, by = wgid / nxt;
  const long rowA = (long)by * 128;
  const long rowB = (long)bx * 128;

  f32x4 acc[4][4];
  const f32x4 z4 = {0.f, 0.f, 0.f, 0.f};
#pragma unroll
  for (int i = 0; i < 4; ++i)
#pragma unroll
    for (int j = 0; j < 4; ++j) acc[i][j] = z4;

  // per-thread staging sources (rows tid>>2 and +64; same XOR key both)
  const int srow = tid >> 2, s4 = tid & 3;
  const long ldk64 = (long)64 * K;
  const bf16_t* Asrc = A + (rowA + srow) * (long)K + ((s4 ^ ((srow >> 1) & 3)) << 3);
  const bf16_t* Bsrc = B + (rowB + srow) * (long)K + ((s4 ^ ((srow >> 1) & 3)) << 3);

  char* p0 = lds;            // slot W: holds tile t
  char* p1 = lds + 16384;    // slot R: holds tile t+1
  char* p2 = lds + 32768;    // slot I: tile t+2 landing
  const int nt = K >> 5;

  bf16x8 afA[4], bfA[4], afB[4], bfB[4];

  // prologue: stage tiles 0,1,2; read frags(0); ensure tile1 resident
  stage_slot(Asrc, Bsrc, ldk64, 0,  p0, tid);
  stage_slot(Asrc, Bsrc, ldk64, 32, p1, tid);
  stage_slot(Asrc, Bsrc, ldk64, 64, p2, tid);
  asm volatile("s_waitcnt vmcnt(8)" ::: "memory");
  __builtin_amdgcn_s_barrier();
  load_frags(p0, wm, wn, lg, lr, afA, bfA);
  asm volatile("s_waitcnt lgkmcnt(0)" ::: "memory");
  __builtin_amdgcn_sched_barrier(0);
  asm volatile("s_waitcnt vmcnt(4)" ::: "memory");
  __builtin_amdgcn_s_barrier();

#define GSTEP(T, afC, bfC, afN, bfN, SR, SW)                                 \
  {                                                                          \
    load_frags(SR, wm, wn, lg, lr, afN, bfN);                                \
    if ((T) + 3 < nt) stage_slot(Asrc, Bsrc, ldk64, ((T) + 3) * 32, SW, tid);\
    __builtin_amdgcn_s_setprio(1);                                           \
    mfma16(afC, bfC, acc);                                                   \
    __builtin_amdgcn_s_setprio(0);                                           \
    asm volatile("s_waitcnt lgkmcnt(0)" ::: "memory");                       \
    __builtin_amdgcn_sched_barrier(0);                                       \
    if ((T) + 3 < nt) { asm volatile("s_waitcnt vmcnt(4)" ::: "memory"); }   \
    else              { asm volatile("s_waitcnt vmcnt(0)" ::: "memory"); }   \
    __builtin_amdgcn_s_barrier();                                            \
  }

  int t = 0;
  for (; t < nt - 2; t += 2) {
    GSTEP(t,     afA, bfA, afB, bfB, p1, p0);
    GSTEP(t + 1, afB, bfB, afA, bfA, p2, p1);
    char* tmp = p2; p2 = p1; p1 = p0; p0 = tmp;  // (W,R,I) <- (oldI, oldW-ish) rotation
  }
  // t == nt-2: read frags(nt-1), MFMA frags(nt-2); then final MFMA
  GSTEP(t, afA, bfA, afB, bfB, p1, p0);
  __builtin_amdgcn_s_setprio(1);
  mfma16(afB, bfB, acc);
  __builtin_amdgcn_s_setprio(0);
#undef GSTEP

  const long crow = rowA + wm * 64;
  const long ccol = rowB + wn * 64;
  if (OUTF32) {
    float* C = (float*)Cout;
#pragma unroll
    for (int mf = 0; mf < 4; ++mf)
#pragma unroll
      for (int j = 0; j < 4; ++j) {
        long row = crow + mf * 16 + lg * 4 + j;
        float* cp = C + row * N + ccol + lr;
#pragma unroll
        for (int nf = 0; nf < 4; ++nf) cp[nf * 16] = acc[mf][nf][j];
      }
  } else {
    unsigned short* C = (unsigned short*)Cout;
#pragma unroll
    for (int mf = 0; mf < 4; ++mf)
#pragma unroll
      for (int j = 0; j < 4; ++j) {
        long row = crow + mf * 16 + lg * 4 + j;
        unsigned short* cp = C + row * N + ccol + lr;
#pragma unroll
        for (int nf = 0; nf < 4; ++nf) cp[nf * 16] = f2bf(acc[mf][nf][j]);
      }
  }
}

// In-place RoPE on bf16 qkv buffer (q heads 0..31, k heads 32..39).
__global__ __launch_bounds__(256) void rope_kernel(unsigned int* __restrict__ qkv32,
                                                   const float* __restrict__ cosb,
                                                   const float* __restrict__ sinb) {
  int t = blockIdx.x * 256 + threadIdx.x;
  int i  = t & 63;
  int sh = t >> 6;
  int hh = sh % 40;
  int s  = sh / 40;
  int col2 = (hh < 32) ? (hh * 64 + i) : (2048 + (hh - 32) * 64 + i);
  unsigned int* p = qkv32 + (long)s * (QKVN / 2) + col2;
  unsigned int v = *p;
  float tr = __builtin_bit_cast(float, (v & 0xffffu) << 16);
  float ti = __builtin_bit_cast(float, v & 0xffff0000u);
  float c  = cosb[s * 64 + i];
  float sn = sinb[s * 64 + i];
  float orr = tr * c - ti * sn;
  float oi  = tr * sn + ti * c;
  *p = (unsigned int)f2bf(orr) | ((unsigned int)f2bf(oi) << 16);
}

// V transpose: vT[kh][hd][s] from qkv[s][5120 + kh*128 + hd].
__global__ __launch_bounds__(256) void vtrans_kernel(const bf16_t* __restrict__ qkv,
                                                     bf16_t* __restrict__ vT) {
  const int kh = blockIdx.x;
  const int hd = threadIdx.x & 127;
  const int s0 = blockIdx.y * 16 + (threadIdx.x >> 7) * 8;
  u16x8 v;
#pragma unroll
  for (int e = 0; e < 8; ++e)
    v[e] = *(const unsigned short*)(qkv + (long)(s0 + e) * QKVN + 5120 + kh * HDIM + hd);
  *(u16x8*)(vT + ((long)kh * HDIM + hd) * S_LEN + s0) = v;
}

// Flash attention: block = (64 q-rows, 1 head), 4 waves x 16 q-rows, KVBLK=64.
__global__ __launch_bounds__(256) void attn_kernel(const bf16_t* __restrict__ qkv,
                                                   const bf16_t* __restrict__ vT,
                                                   unsigned short* __restrict__ ob) {
  __shared__ bf16_t Kt[64 * 128];
  __shared__ bf16_t Vt[128 * 64];
  __shared__ bf16_t Pl[4 * 16 * 64];
  const int h  = blockIdx.x;
  const int qi = 31 - blockIdx.y;
  const int qb = qi * 64;
  const int kh = h >> 2;
  const int tid = threadIdx.x, lane = tid & 63, w = tid >> 6;
  const int lg = lane >> 4, lr = lane & 15;
  const int qrow0 = qb + w * 16;

  bf16x8 qf[4];
  const bf16_t* qptr = qkv + (long)(qrow0 + lr) * QKVN + h * HDIM + lg * 8;
#pragma unroll
  for (int kk = 0; kk < 4; ++kk) qf[kk] = *(const bf16x8*)(qptr + kk * 32);

  const f32x4 z4 = {0.f, 0.f, 0.f, 0.f};
  f32x4 oacc[8];
#pragma unroll
  for (int c = 0; c < 8; ++c) oacc[c] = z4;
  float m[4]    = {-1e30f, -1e30f, -1e30f, -1e30f};
  float lsum[4] = {0.f, 0.f, 0.f, 0.f};

  char* KtB = (char*)Kt;
  char* VtB = (char*)Vt;
  char* PlB = (char*)Pl + w * 2048;
  const float scale = 0.08838834764831845f;
  const int ntiles = qi + 1;

  for (int t = 0; t < ntiles; ++t) {
    const int kv0 = t * 64;
    __syncthreads();
#pragma unroll
    for (int it = 0; it < 4; ++it) {
      int cch = tid + it * 256;
      int r = cch >> 4, c = cch & 15;
      const bf16_t* src = qkv + (long)(kv0 + r) * QKVN + 4096 + kh * HDIM
                          + ((c ^ (r & 7)) * 8);
      gload_lds16(src, KtB + cch * 16);
    }
#pragma unroll
    for (int it = 0; it < 4; ++it) {
      int cch = tid + it * 256;
      int hd = cch >> 3, c = cch & 7;
      const bf16_t* src = vT + ((long)kh * HDIM + hd) * S_LEN + kv0
                          + ((c ^ (hd & 7)) * 8);
      gload_lds16(src, VtB + cch * 16);
    }
    __syncthreads();

    f32x4 sf[4];
#pragma unroll
    for (int f = 0; f < 4; ++f) {
      f32x4 a = z4;
      int n = f * 16 + lr;
      int rb = n * 256, sw = (n & 7) << 4;
#pragma unroll
      for (int kk = 0; kk < 4; ++kk) {
        bf16x8 kf = *(const bf16x8*)(KtB + rb + (((kk * 4 + lg) * 16) ^ sw));
        a = __builtin_amdgcn_mfma_f32_16x16x32_bf16(qf[kk], kf, a, 0, 0, 0);
      }
      sf[f] = a;
    }

    float sc_arr[4];
#pragma unroll
    for (int j = 0; j < 4; ++j) {
      int qrow = qrow0 + lg * 4 + j;
      float sv[4];
#pragma unroll
      for (int f = 0; f < 4; ++f) {
        float s = sf[f][j] * scale;
        if (kv0 + f * 16 + lr > qrow) s = -1e9f;
        sv[f] = s;
      }
      float mx = fmaxf(fmaxf(sv[0], sv[1]), fmaxf(sv[2], sv[3]));
      mx = fmaxf(mx, __shfl_xor(mx, 1));
      mx = fmaxf(mx, __shfl_xor(mx, 2));
      mx = fmaxf(mx, __shfl_xor(mx, 4));
      mx = fmaxf(mx, __shfl_xor(mx, 8));
      float mn = fmaxf(m[j], mx);
      float p[4];
#pragma unroll
      for (int f = 0; f < 4; ++f) p[f] = __expf(sv[f] - mn);
      float ps = (p[0] + p[1]) + (p[2] + p[3]);
      ps += __shfl_xor(ps, 1);
      ps += __shfl_xor(ps, 2);
      ps += __shfl_xor(ps, 4);
      ps += __shfl_xor(ps, 8);
      float sc = __expf(m[j] - mn);
      lsum[j] = lsum[j] * sc + ps;
      m[j] = mn;
      sc_arr[j] = sc;
      int row = lg * 4 + j;
      int swp = (row & 7) << 4;
#pragma unroll
      for (int f = 0; f < 4; ++f)
        *(unsigned short*)(PlB + row * 128 + (((f * 16 + lr) * 2) ^ swp)) = f2bf(p[f]);
    }
#pragma unroll
    for (int c = 0; c < 8; ++c)
#pragma unroll
      for (int j = 0; j < 4; ++j) oacc[c][j] *= sc_arr[j];

    bf16x8 pfr[2];
#pragma unroll
    for (int kk = 0; kk < 2; ++kk)
      pfr[kk] = *(const bf16x8*)(PlB + lr * 128 + (((kk * 4 + lg) * 16) ^ ((lr & 7) << 4)));
#pragma unroll
    for (int c = 0; c < 8; ++c) {
      int hd = c * 16 + lr;
      int rb = hd * 128, sw = (hd & 7) << 4;
#pragma unroll
      for (int kk = 0; kk < 2; ++kk) {
        bf16x8 vf = *(const bf16x8*)(VtB + rb + (((kk * 4 + lg) * 16) ^ sw));
        oacc[c] = __builtin_amdgcn_mfma_f32_16x16x32_bf16(pfr[kk], vf, oacc[c], 0, 0, 0);
      }
    }
  }

  float rl[4];
#pragma unroll
  for (int j = 0; j < 4; ++j) rl[j] = 1.f / lsum[j];
#pragma unroll
  for (int c = 0; c < 8; ++c)
#pragma unroll
    for (int j = 0; j < 4; ++j) {
      long row = qrow0 + lg * 4 + j;
      ob[row * 4096 + h * 128 + c * 16 + lr] = f2bf(oacc[c][j] * rl[j]);
    }
}

extern "C" void kernel_launch(void* const* d_in, const int* in_sizes, int n_in,
                              void* d_out, int out_size, void* d_ws, size_t ws_size,
                              hipStream_t stream) {
  const float* x  = (const float*)d_in[0];
  const float* wq = (const float*)d_in[1];
  const float* wk = (const float*)d_in[2];
  const float* wv = (const float*)d_in[3];
  const float* wo = (const float*)d_in[4];
  const float* fc = (const float*)d_in[5];
  const float* fs = (const float*)d_in[6];

  char* ws = (char*)d_ws;
  bf16_t* xb    = (bf16_t*)(ws + 0);          // 2048x4096 (dead after gemm1)
  bf16_t* wqkvb = (bf16_t*)(ws + 16777216);   // 6144x4096
  bf16_t* wob   = (bf16_t*)(ws + 67108864);   // 4096x4096
  bf16_t* qkv   = (bf16_t*)(ws + 100663296);  // 2048x6144
  bf16_t* ob    = (bf16_t*)(ws + 125829120);  // 2048x4096
  bf16_t* vT    = (bf16_t*)(ws + 0);          // 8x128x2048 (4 MB, reuses xb)

  cvt_kernel<<<2048, 256, 0, stream>>>(x,  (unsigned short*)xb,                    (2048 * 4096) / 4);
  cvt_kernel<<<2048, 256, 0, stream>>>(wq, (unsigned short*)wqkvb,                 (4096 * 4096) / 4);
  cvt_kernel<<<1024, 256, 0, stream>>>(wk, (unsigned short*)(wqkvb + 4096 * 4096), (1024 * 4096) / 4);
  cvt_kernel<<<1024, 256, 0, stream>>>(wv, (unsigned short*)(wqkvb + 5120 * 4096), (1024 * 4096) / 4);
  cvt_kernel<<<2048, 256, 0, stream>>>(wo, (unsigned short*)wob,                   (4096 * 4096) / 4);

  gemm_pipe<0><<<768, 256, 0, stream>>>(xb, wqkvb, qkv, 2048, 6144, 4096, 48);
  vtrans_kernel<<<dim3(8, 128), 256, 0, stream>>>(qkv, vT);
  rope_kernel<<<20480, 256, 0, stream>>>((unsigned int*)qkv, fc, fs);
  attn_kernel<<<dim3(32, 32), 256, 0, stream>>>(qkv, vT, (unsigned short*)ob);
  gemm_pipe<1><<<512, 256, 0, stream>>>(ob, wob, d_out, 2048, 4096, 4096, 32);
}